// Round 8
// baseline (163.072 us; speedup 1.0000x reference)
//
#include <hip/hip_runtime.h>

// Gammatone filterbank, truncated-history, stage-skewed, SCALAR-FMA form.
// v8: two untested mechanisms, structure otherwise = v7 (which proved
// prefetch-depth/unroll/makespan all neutral -- kernel sits on ~71us floor):
//  (a) De-vectorized complex math. v2-v7 used f32x2 ext-vectors with a
//      `.yx` swizzle per stage, betting the backend folds it into
//      v_pk_fma_f32 op_sel. If it instead emits scalar FMAs + v_mov pairs,
//      each sample costs ~24+ VALU instrs (~48+ cyc issue) -- an
//      issue-bound SIMD, consistent with v4's "TLP doesn't help" data.
//      Explicit real/imag SSA: 16 v_fma_f32 per sample, 8 independent
//      2-FMA chains, ZERO shuffles, no pack/unpack.
//  (b) Non-temporal output stores. The harness poison-fill leaves L2 fully
//      dirty; our 131 MB write stream then write-allocates through L2,
//      evicting dirty lines ahead of itself. nt stores stream past L2
//      (output is never re-read).
// Skew invariant (from v2): at iteration i regs hold s1=y1[i+2],
// s2=y2[i+1], s3=y3[i], s4=y4[i-1]; all 4 updates read pre-update values.

#define B_N    8
#define T_LEN  32000
#define C_CH   128
#define L_CHK  500
#define NB     64          // T_LEN / L_CHK
#define W_MAX  1024

// One skewed pipeline step, consuming x[i+3]. Complex updates written as
// scalar FMA SSA:  n = c*s + a  ->  nr = fma(-ci,si, fma(cr,sr,ar)),
//                                   ni = fma( ci,sr, fma(cr,si,ai)).
#define PSTEP(XR) do {                                        \
    float n4r = fmaf(cr, s4r, s3r); n4r = fmaf(mci, s4i, n4r); \
    float n4i = fmaf(cr, s4i, s3i); n4i = fmaf(ci,  s4r, n4i); \
    float n3r = fmaf(cr, s3r, s2r); n3r = fmaf(mci, s3i, n3r); \
    float n3i = fmaf(cr, s3i, s2i); n3i = fmaf(ci,  s3r, n3i); \
    float n2r = fmaf(cr, s2r, s1r); n2r = fmaf(mci, s2i, n2r); \
    float n2i = fmaf(cr, s2i, s1i); n2i = fmaf(ci,  s2r, n2i); \
    float n1r = fmaf(cr, s1r, (XR)); n1r = fmaf(mci, s1i, n1r);\
    float n1i = cr * s1i;           n1i = fmaf(ci,  s1r, n1i); \
    s4r = n4r; s4i = n4i; s3r = n3r; s3i = n3i;               \
    s2r = n2r; s2i = n2i; s1r = n1r; s1i = n1i;               \
} while (0)

__global__ __launch_bounds__(64, 1) void gt_trunc(
    const float* __restrict__ x, const float* __restrict__ cre,
    const float* __restrict__ cim, const float* __restrict__ fac,
    float* __restrict__ out)
{
    __shared__ __align__(16) float xs[W_MAX + L_CHK + 16];
    const int g  = blockIdx.x;            // channel half (0: ch 0-63, 1: ch 64-127)
    const int k  = blockIdx.y;            // time chunk
    const int b  = blockIdx.z;            // batch
    const int c  = g * 64 + threadIdx.x;
    const int t0 = k * L_CHK;

    // Warm-up length from the largest-|c| channel of this half. A=14
    // (validated v5/v7: absmax stays at the 0.00390625 harness floor).
    const float cr0 = cre[g * 64], ci0 = cim[g * 64];
    const float negln = -0.5f * __logf(cr0 * cr0 + ci0 * ci0);   // -ln|c|
    int W = (int)ceilf(14.0f / negln) + 2;
    W = (W + 3) & ~3;                      // multiple of 4 (float4 LDS reads)
    if (W > W_MAX) W = W_MAX;
    int start = t0 - W;
    if (start < 0) start = 0;              // early chunks: zero init is exact
    const int n  = t0 + L_CHK - start;     // staged samples (multiple of 4)
    const int nw = t0 - start;             // warm-up steps (multiple of 4)

    // Stage x[start .. t0+L) into LDS at xs[1..n] (shift by 1: skewed
    // consumption index i+3 lands on aligned quads), coalesced. Zero-fill
    // 12 tail slots (2-deep prefetch reads up to xs[nw+511]; past-n data
    // only feeds dead s1..s3 but must not be garbage).
    const float* xb = x + (size_t)b * T_LEN + start;
    for (int i = threadIdx.x; i < n; i += 64) xs[i + 1] = xb[i];
    if (threadIdx.x < 12) xs[n + 1 + threadIdx.x] = 0.f;

    const float cr = cre[c], ci = cim[c], f = fac[c];
    const float mci = -ci;
    __syncthreads();

    // Pipeline fill in closed form from zero state (x0..x2 = xs[1..3]):
    //   y1[0]=(x0,0); y1[1]=c*y1[0]+x1; s1=y1[2]=c*y1[1]+x2;
    //   y2[0]=y1[0];  s2=y2[1]=c*y2[0]+y1[1]; s3=y3[0]=y2[0]=(x0,0); s4=0.
    const float x0 = xs[1], x1 = xs[2], x2 = xs[3];
    const float y11r = fmaf(cr, x0, x1);
    const float y11i = ci * x0;
    float s1r = fmaf(mci, y11i, fmaf(cr, y11r, x2));
    float s1i = fmaf(ci, y11r, cr * y11i);
    float s2r = fmaf(cr, x0, y11r);
    float s2i = fmaf(ci, x0, y11i);
    float s3r = x0, s3i = 0.f;
    float s4r = 0.f, s4i = 0.f;

    // Warm-up (no stores). 2-deep software pipeline (v7).
    float4 q0 = *(const float4*)&xs[4];
    float4 q1 = *(const float4*)&xs[8];
    #pragma unroll 2
    for (int i = 0; i < nw; i += 4) {
        const float4 q2 = *(const float4*)&xs[i + 12];
        PSTEP(q0.x); PSTEP(q0.y); PSTEP(q0.z); PSTEP(q0.w);
        q0 = q1; q1 = q2;
    }
    // loop exit: q0 = xs[nw+4..7], q1 = xs[nw+8..11]

    // Output region: after the step at iteration i, s4 = y4[i]; store for
    // i >= nw. Non-temporal: stream past L2, output is never re-read.
    float* op = out + ((size_t)b * T_LEN + t0) * C_CH + c;
    #pragma unroll 2
    for (int i = nw; i < nw + L_CHK; i += 4) {
        const float4 q2 = *(const float4*)&xs[i + 12];
        PSTEP(q0.x); __builtin_nontemporal_store(s4r * f, &op[0 * C_CH]);
        PSTEP(q0.y); __builtin_nontemporal_store(s4r * f, &op[1 * C_CH]);
        PSTEP(q0.z); __builtin_nontemporal_store(s4r * f, &op[2 * C_CH]);
        PSTEP(q0.w); __builtin_nontemporal_store(s4r * f, &op[3 * C_CH]);
        op += 4 * (size_t)C_CH;
        q0 = q1; q1 = q2;
    }
}

extern "C" void kernel_launch(void* const* d_in, const int* in_sizes, int n_in,
                              void* d_out, int out_size, void* d_ws, size_t ws_size,
                              hipStream_t stream) {
    const float* x   = (const float*)d_in[0];
    const float* cre = (const float*)d_in[1];
    const float* cim = (const float*)d_in[2];
    const float* fac = (const float*)d_in[3];
    float* out = (float*)d_out;

    gt_trunc<<<dim3(2, NB, B_N), 64, 0, stream>>>(x, cre, cim, fac, out);
}